// Round 21
// baseline (403.399 us; speedup 1.0000x reference)
//
#include <hip/hip_runtime.h>
#include <math.h>

#define NR 131072
#define KC 1024
#define DD 256

// d_out element offsets (float32 elements)
#define ZQ_OFF  0
#define RES_OFF 33554432
#define IDX_OFF 67108864
#define LOSS_OFF 67239936
#define PERP_OFF 67239937

// ws byte offsets (total ~1.06 MB)
#define WS_CNT 0          // int[1024]
#define WS_C2N 4096       // float[1024]
#define WS_IDX 8192       // int[131072] = 512KB
#define WS_BSS 532480     // double[2048]
#define WS_CBS 548864     // ushort cbs hi-only: 64 tiles x 8KB = 512KB

#define MARG 5e-4f
#define CCAP 24

#define FM(x,y) __fmul_rn((x),(y))
#define FA(x,y) __fadd_rn((x),(y))

typedef __attribute__((ext_vector_type(8))) short bf16x8;
typedef __attribute__((ext_vector_type(4))) float f32x4;

static __device__ __forceinline__ unsigned short bf16h(float f) {
  unsigned int u = __float_as_uint(f);
  u += 0x7FFFu + ((u >> 16) & 1u);
  return (unsigned short)(u >> 16);
}

// ---- numpy f32 pairwise sum-of-squares, one 128-block (AVX512 tree) --------
static __device__ __forceinline__ float np_sumsq128(const float* __restrict__ q) {
  float lane[16];
#pragma unroll
  for (int l = 0; l < 16; l++) {
    float s0 = FM(q[l +   0], q[l +   0]);
    float s1 = FM(q[l +  16], q[l +  16]);
    float s2 = FM(q[l +  32], q[l +  32]);
    float s3 = FM(q[l +  48], q[l +  48]);
    float s4 = FM(q[l +  64], q[l +  64]);
    float s5 = FM(q[l +  80], q[l +  80]);
    float s6 = FM(q[l +  96], q[l +  96]);
    float s7 = FM(q[l + 112], q[l + 112]);
    lane[l] = FA(FA(FA(s0, s1), FA(s2, s3)), FA(FA(s4, s5), FA(s6, s7)));
  }
#pragma unroll
  for (int h = 8; h >= 1; h >>= 1)
#pragma unroll
    for (int l = 0; l < 8; l++)
      if (l < h) lane[l] = FA(lane[l], lane[l + h]);
  return lane[0];
}

static __device__ __forceinline__ float np_sumsq256(const float* __restrict__ p) {
  return FA(np_sumsq128(p), np_sumsq128(p + 128));
}

// ---------------- K1a: codebook c2 (numpy-replica f32) ----------------------
__global__ void vqv_c2(const float* __restrict__ cb, float* __restrict__ c2n) {
  const int code = blockIdx.x * 256 + threadIdx.x;
  if (code < KC) c2n[code] = np_sumsq256(cb + (size_t)code * DD);
}

// ---------------- K1b: codebook bf16 hi split, MFMA-granule layout ----------
__global__ void vqv_cbsplit(const float* __restrict__ cb,
                            unsigned short* __restrict__ cbs) {
  const int g  = blockIdx.x * 256 + threadIdx.x;   // 0..32767
  const int t  = g >> 9;
  const int gi = g & 511;
  const int kc = gi >> 6, q = (gi >> 4) & 3, c = gi & 15;
  const float* src = cb + (size_t)(t * 16 + c) * DD + kc * 32 + q * 8;
  unsigned int w[4];
#pragma unroll
  for (int p = 0; p < 4; p++)
    w[p] = (unsigned int)bf16h(src[p * 2]) |
           ((unsigned int)bf16h(src[p * 2 + 1]) << 16);
  *(uint4*)(cbs + (size_t)g * 8) = make_uint4(w[0], w[1], w[2], w[3]);
}

// ---------------- K2: screen + finalize (no-spill register budget) ----------
// r20's kernel with ONE change: __launch_bounds__(256, 3) -> ~168 VGPR
// budget, so the 64-VGPR loop-invariant zH fragment set stays in registers
// (r19/r20 spilled ~160B/thread to scratch: the constant 42.6MB WRITE_SIZE
// and per-tile scratch reloads were the screen's dominant stall).
__global__ __launch_bounds__(256, 3) void vqv_main(
    const float* __restrict__ z, const float* __restrict__ cb,
    const unsigned short* __restrict__ cbs,
    const float* __restrict__ c2n,
    float* __restrict__ out, int* __restrict__ counts,
    int* __restrict__ idxw) {
  __shared__ unsigned short ccode[128][CCAP];           //  6 KB
  __shared__ float cd[128][CCAP];                       // 12 KB
  __shared__ int ccnt[128];
  __shared__ float m1row[128];
  __shared__ float z2s[128];
  __shared__ __align__(16) float c2l[1024];             //  4 KB

  const int tid = threadIdx.x, wg = blockIdx.x;
  const int wv = tid >> 6, ln = tid & 63;
  const int rl = ln & 15;           // row within group
  const int qk = ln >> 4;           // k-octet / code-quad selector
  const int rowg0 = wg * 128 + wv * 32 + rl;      // group-0 global row

  // ---- c2 into LDS: every wave loads ALL of it (benign same-value race) ----
#pragma unroll
  for (int i = 0; i < 4; i++)
    ((float4*)c2l)[i * 64 + ln] = ((const float4*)c2n)[i * 64 + ln];
  // ---- per-wave candidate-count init ----
  if (ln < 32) ccnt[wv * 32 + ln] = 0;

  // ---- build z hi-fragments in registers for both row-groups ----
  bf16x8 zH0[8], zH1[8];
#pragma unroll
  for (int kc = 0; kc < 8; kc++) {
    const float4* p0 = (const float4*)(z + (size_t)rowg0 * DD + kc * 32 + qk * 8);
    const float4* p1 = (const float4*)(z + (size_t)(rowg0 + 16) * DD + kc * 32 + qk * 8);
    const float4 a0 = p0[0], b0 = p0[1];
    const float4 a1 = p1[0], b1 = p1[1];
    zH0[kc][0] = (short)bf16h(a0.x); zH0[kc][1] = (short)bf16h(a0.y);
    zH0[kc][2] = (short)bf16h(a0.z); zH0[kc][3] = (short)bf16h(a0.w);
    zH0[kc][4] = (short)bf16h(b0.x); zH0[kc][5] = (short)bf16h(b0.y);
    zH0[kc][6] = (short)bf16h(b0.z); zH0[kc][7] = (short)bf16h(b0.w);
    zH1[kc][0] = (short)bf16h(a1.x); zH1[kc][1] = (short)bf16h(a1.y);
    zH1[kc][2] = (short)bf16h(a1.z); zH1[kc][3] = (short)bf16h(a1.w);
    zH1[kc][4] = (short)bf16h(b1.x); zH1[kc][5] = (short)bf16h(b1.y);
    zH1[kc][6] = (short)bf16h(b1.z); zH1[kc][7] = (short)bf16h(b1.w);
  }

  // ---- z2 (exact np AVX512 tree), wave-own rows only ----
  {
    const int gg = ln >> 4, l = ln & 15;
#pragma unroll 1
    for (int g4 = 0; g4 < 8; g4++) {
      const int rlcl = wv * 32 + g4 * 4 + gg;
      const float* q = z + (size_t)(wg * 128 + rlcl) * DD;
      float blk[2];
#pragma unroll
      for (int b = 0; b < 2; b++) {
        const float* qq = q + b * 128;
        const float s0 = FM(qq[l +   0], qq[l +   0]);
        const float s1 = FM(qq[l +  16], qq[l +  16]);
        const float s2 = FM(qq[l +  32], qq[l +  32]);
        const float s3 = FM(qq[l +  48], qq[l +  48]);
        const float s4 = FM(qq[l +  64], qq[l +  64]);
        const float s5 = FM(qq[l +  80], qq[l +  80]);
        const float s6 = FM(qq[l +  96], qq[l +  96]);
        const float s7 = FM(qq[l + 112], qq[l + 112]);
        float v = FA(FA(FA(s0, s1), FA(s2, s3)), FA(FA(s4, s5), FA(s6, s7)));
#pragma unroll
        for (int h = 8; h >= 1; h >>= 1) v = FA(v, __shfl_down(v, h, 16));
        blk[b] = v;
      }
      if (l == 0) z2s[rlcl] = FA(blk[0], blk[1]);
    }
  }

  const float z2v0 = z2s[wv * 32 + rl];
  const float z2v1 = z2s[wv * 32 + rl + 16];
  const int rw0 = wv * 32 + rl;

  float m10 = INFINITY, m11 = INFINITY;
#pragma unroll 2
  for (int t = 0; t < 64; t++) {
    f32x4 accA = {0.f, 0.f, 0.f, 0.f}, accB = accA;
    // load-and-consume A-fragments (L2-resident cbs, coalesced 1KB/load);
    // with the 168-VGPR budget the compiler pipelines these across tiles.
#pragma unroll
    for (int kc = 0; kc < 8; kc++) {
      const bf16x8 aH = *(const bf16x8*)(cbs + (size_t)t * 4096 + kc * 512 + ln * 8);
      accA = __builtin_amdgcn_mfma_f32_16x16x32_bf16(aH, zH0[kc], accA, 0, 0, 0);
      accB = __builtin_amdgcn_mfma_f32_16x16x32_bf16(aH, zH1[kc], accB, 0, 0, 0);
    }
    // fold: lane covers codes t*16 + qk*4 + r, rows (group0, group1)
    const float4 c2v4 = *(const float4*)&c2l[t * 16 + qk * 4];
    float dh0[4], dh1[4];
#pragma unroll
    for (int r = 0; r < 4; r++) {
      const float c2v = r == 0 ? c2v4.x : r == 1 ? c2v4.y : r == 2 ? c2v4.z : c2v4.w;
      dh0[r] = z2v0 - 2.f * accA[r] + c2v;
      dh1[r] = z2v1 - 2.f * accB[r] + c2v;
      m10 = fminf(m10, dh0[r]);
      m11 = fminf(m11, dh1[r]);
    }
    m10 = fminf(m10, __shfl_xor(m10, 16));
    m10 = fminf(m10, __shfl_xor(m10, 32));
    m11 = fminf(m11, __shfl_xor(m11, 16));
    m11 = fminf(m11, __shfl_xor(m11, 32));
#pragma unroll
    for (int r = 0; r < 4; r++) {
      if (dh0[r] <= m10 + MARG) {
        const int s = atomicAdd(&ccnt[rw0], 1);
        if (s < CCAP) {
          ccode[rw0][s] = (unsigned short)(t * 16 + qk * 4 + r);
          cd[rw0][s] = dh0[r];
        }
      }
      if (dh1[r] <= m11 + MARG) {
        const int s = atomicAdd(&ccnt[rw0 + 16], 1);
        if (s < CCAP) {
          ccode[rw0 + 16][s] = (unsigned short)(t * 16 + qk * 4 + r);
          cd[rw0 + 16][s] = dh1[r];
        }
      }
    }
  }

  if (qk == 0) { m1row[rw0] = m10; m1row[rw0 + 16] = m11; }
  // (no barrier: all state is wave-own)

  // ---- finalize (wave-own rows: lanes 0..31 -> rows wv*32+ln) ----
  if (ln < 32) {
    const int rwl = wv * 32 + ln;
    const int row = wg * 128 + rwl;
    const float mf = m1row[rwl] + MARG;
    const int nc = ccnt[rwl];
    int best;
    if (nc > CCAP) {             // overflow (P~0): full exact np scan
      const float* zr = z + (size_t)row * DD;
      const float z2r = z2s[rwl];
      float db = INFINITY; best = 0;
      for (int c = 0; c < KC; c++) {
        const float* cr = cb + (size_t)c * DD;
        float dot = 0.f;
#pragma unroll 8
        for (int k = 0; k < DD; k++) dot = __fmaf_rn(zr[k], cr[k], dot);
        const float t1 = 2.0f * dot;
        const float d = FA(FA(z2r, -t1), c2l[c]);
        if (d < db) { db = d; best = c; }          // ascending c: first-min
      }
    } else {
      int kept = 0, kcode = 0;
      for (int s = 0; s < nc; s++)
        if (cd[rwl][s] <= mf) { kept++; kcode = ccode[rwl][s]; }
      if (kept == 1) best = kcode;
      else {
        const float* zr = z + (size_t)row * DD;
        const float z2r = z2s[rwl];
        float db = INFINITY; int bi = 0x7FFFFFFF;
        for (int s = 0; s < nc; s++) {
          if (cd[rwl][s] > mf) continue;
          const int c = ccode[rwl][s];
          const float* cr = cb + (size_t)c * DD;
          float dot = 0.f;
#pragma unroll 8
          for (int k = 0; k < DD; k++) dot = __fmaf_rn(zr[k], cr[k], dot);
          const float t1 = 2.0f * dot;
          const float d = FA(FA(z2r, -t1), c2l[c]);   // exact np-f32 d
          if (d < db || (d == db && c < bi)) { db = d; bi = c; }
        }
        best = bi;
      }
    }
    atomicAdd(&counts[best], 1);
    idxw[row] = best;
    out[IDX_OFF + row] = (float)best;
  }
}

// ---------------- K3: streaming epilogue (gather + outputs + loss) ----------
__global__ __launch_bounds__(256) void vqv_out(
    const float* __restrict__ z, const float* __restrict__ cb,
    const int* __restrict__ idxw, float* __restrict__ out,
    double* __restrict__ bss) {
  __shared__ double wred[4];
  const int wv = threadIdx.x >> 6, ln = threadIdx.x & 63;
  const int rowbase = (blockIdx.x * 4 + wv) * 16;

  float ss = 0.f;
#pragma unroll 1
  for (int g = 0; g < 16; g += 8) {
    float4 r4b[8], q4b[8];
#pragma unroll
    for (int u = 0; u < 8; u++) {
      const size_t zrow = (size_t)(rowbase + g + u) * DD;
      r4b[u] = ((const float4*)(z + zrow))[ln];
      q4b[u] = ((const float4*)(cb + (size_t)idxw[rowbase + g + u] * DD))[ln];
    }
#pragma unroll
    for (int u = 0; u < 8; u++) {
      const size_t zrow = (size_t)(rowbase + g + u) * DD;
      const float4 r4 = r4b[u];
      const float4 q4 = q4b[u];
      float4 stv, rsv; float dq;
      stv.x = r4.x + (q4.x - r4.x); rsv.x = r4.x - q4.x; dq = q4.x - r4.x; ss = fmaf(dq, dq, ss);
      stv.y = r4.y + (q4.y - r4.y); rsv.y = r4.y - q4.y; dq = q4.y - r4.y; ss = fmaf(dq, dq, ss);
      stv.z = r4.z + (q4.z - r4.z); rsv.z = r4.z - q4.z; dq = q4.z - r4.z; ss = fmaf(dq, dq, ss);
      stv.w = r4.w + (q4.w - r4.w); rsv.w = r4.w - q4.w; dq = q4.w - r4.w; ss = fmaf(dq, dq, ss);
      ((float4*)(out + ZQ_OFF  + zrow))[ln] = stv;
      ((float4*)(out + RES_OFF + zrow))[ln] = rsv;
    }
  }
  double dss = (double)ss;
  for (int o = 32; o; o >>= 1) dss += __shfl_down(dss, o, 64);
  if (ln == 0) wred[wv] = dss;
  __syncthreads();
  if (threadIdx.x == 0) bss[blockIdx.x] = wred[0] + wred[1] + wred[2] + wred[3];
}

// ---------------- K4: scalars (loss, perplexity) ----------------------------
__global__ void vqv_final(const int* __restrict__ counts,
                          const double* __restrict__ bss,
                          float* __restrict__ out) {
  __shared__ double red[256];
  const int t = threadIdx.x;
  double s = 0.0;
  for (int i = t; i < 2048; i += 256) s += bss[i];
  red[t] = s; __syncthreads();
  for (int s2 = 128; s2 > 0; s2 >>= 1) { if (t < s2) red[t] += red[t + s2]; __syncthreads(); }
  const double ssq = red[0];
  __syncthreads();
  double h = 0.0;
  for (int c = t; c < 1024; c += 256) {
    double p = (double)counts[c] / 131072.0;
    h += p * log(p + 1e-10);
  }
  red[t] = h; __syncthreads();
  for (int s2 = 128; s2 > 0; s2 >>= 1) { if (t < s2) red[t] += red[t + s2]; __syncthreads(); }
  if (t == 0) {
    out[LOSS_OFF] = (float)(0.25 * ssq / 33554432.0);
    out[PERP_OFF] = (float)exp(-red[0]);
  }
}

extern "C" void kernel_launch(void* const* d_in, const int* in_sizes, int n_in,
                              void* d_out, int out_size, void* d_ws, size_t ws_size,
                              hipStream_t stream) {
  // Bind inputs by SIZE: z has 33,554,432 elems, codebook 262,144.
  const float* z;
  const float* cb;
  if (in_sizes[0] == NR * DD) { z = (const float*)d_in[0]; cb = (const float*)d_in[1]; }
  else                        { cb = (const float*)d_in[0]; z = (const float*)d_in[1]; }

  float* out = (float*)d_out;
  char* ws = (char*)d_ws;
  int*            counts = (int*)(ws + WS_CNT);
  float*          c2n    = (float*)(ws + WS_C2N);
  int*            idxw   = (int*)(ws + WS_IDX);
  double*         bssp   = (double*)(ws + WS_BSS);
  unsigned short* cbs    = (unsigned short*)(ws + WS_CBS);

  hipMemsetAsync(counts, 0, 4096, stream);
  vqv_c2<<<4, 256, 0, stream>>>(cb, c2n);
  vqv_cbsplit<<<128, 256, 0, stream>>>(cb, cbs);
  vqv_main<<<NR / 128, 256, 0, stream>>>(z, cb, cbs, c2n, out, counts, idxw);
  vqv_out<<<2048, 256, 0, stream>>>(z, cb, idxw, out, bssp);
  vqv_final<<<1, 256, 0, stream>>>(counts, bssp, out);
}

// Round 22
// 369.462 us; speedup vs baseline: 1.0919x; 1.0919x over previous
//
#include <hip/hip_runtime.h>
#include <math.h>

#define NR 131072
#define KC 1024
#define DD 256

// d_out element offsets (float32 elements)
#define ZQ_OFF  0
#define RES_OFF 33554432
#define IDX_OFF 67108864
#define LOSS_OFF 67239936
#define PERP_OFF 67239937

// ws byte offsets (total ~1.06 MB)
#define WS_CNT 0          // int[1024]
#define WS_C2N 4096       // float[1024]
#define WS_IDX 8192       // int[131072] = 512KB
#define WS_BSS 532480     // double[2048]
#define WS_CBS 548864     // ushort cbs hi-only: 64 tiles x 8KB = 512KB

#define MARG 5e-4f
#define CCAP 24

#define FM(x,y) __fmul_rn((x),(y))
#define FA(x,y) __fadd_rn((x),(y))

typedef __attribute__((ext_vector_type(8))) short bf16x8;
typedef __attribute__((ext_vector_type(4))) float f32x4;

static __device__ __forceinline__ unsigned short bf16h(float f) {
  unsigned int u = __float_as_uint(f);
  u += 0x7FFFu + ((u >> 16) & 1u);
  return (unsigned short)(u >> 16);
}

// ---- numpy f32 pairwise sum-of-squares, one 128-block (AVX512 tree) --------
static __device__ __forceinline__ float np_sumsq128(const float* __restrict__ q) {
  float lane[16];
#pragma unroll
  for (int l = 0; l < 16; l++) {
    float s0 = FM(q[l +   0], q[l +   0]);
    float s1 = FM(q[l +  16], q[l +  16]);
    float s2 = FM(q[l +  32], q[l +  32]);
    float s3 = FM(q[l +  48], q[l +  48]);
    float s4 = FM(q[l +  64], q[l +  64]);
    float s5 = FM(q[l +  80], q[l +  80]);
    float s6 = FM(q[l +  96], q[l +  96]);
    float s7 = FM(q[l + 112], q[l + 112]);
    lane[l] = FA(FA(FA(s0, s1), FA(s2, s3)), FA(FA(s4, s5), FA(s6, s7)));
  }
#pragma unroll
  for (int h = 8; h >= 1; h >>= 1)
#pragma unroll
    for (int l = 0; l < 8; l++)
      if (l < h) lane[l] = FA(lane[l], lane[l + h]);
  return lane[0];
}

static __device__ __forceinline__ float np_sumsq256(const float* __restrict__ p) {
  return FA(np_sumsq128(p), np_sumsq128(p + 128));
}

// ---------------- K1a: codebook c2 (numpy-replica f32) ----------------------
__global__ void vqw_c2(const float* __restrict__ cb, float* __restrict__ c2n) {
  const int code = blockIdx.x * 256 + threadIdx.x;
  if (code < KC) c2n[code] = np_sumsq256(cb + (size_t)code * DD);
}

// ---------------- K1b: codebook bf16 hi split, MFMA-granule layout ----------
__global__ void vqw_cbsplit(const float* __restrict__ cb,
                            unsigned short* __restrict__ cbs) {
  const int g  = blockIdx.x * 256 + threadIdx.x;   // 0..32767
  const int t  = g >> 9;
  const int gi = g & 511;
  const int kc = gi >> 6, q = (gi >> 4) & 3, c = gi & 15;
  const float* src = cb + (size_t)(t * 16 + c) * DD + kc * 32 + q * 8;
  unsigned int w[4];
#pragma unroll
  for (int p = 0; p < 4; p++)
    w[p] = (unsigned int)bf16h(src[p * 2]) |
           ((unsigned int)bf16h(src[p * 2 + 1]) << 16);
  *(uint4*)(cbs + (size_t)g * 8) = make_uint4(w[0], w[1], w[2], w[3]);
}

// ---------------- K2: pipelined screen + finalize ---------------------------
// 64 rows/WG (2048 WGs -> backfill), 4 waves, ONE 16-row group per wave.
// Explicit cur/nxt register double-buffer: tile t+1's 8 L2 loads issue a
// full iteration ahead of use. MFMA chain split into two 4-deep chains.
// Candidate semantics identical to r13-r21 (per-tile cross-lane row min,
// MARG append, CCAP overflow -> exact scan); exact-np rescore unchanged.
__global__ __launch_bounds__(256, 4) void vqw_main(
    const float* __restrict__ z, const float* __restrict__ cb,
    const unsigned short* __restrict__ cbs,
    const float* __restrict__ c2n,
    float* __restrict__ out, int* __restrict__ counts,
    int* __restrict__ idxw) {
  __shared__ unsigned short ccode[64][CCAP];            //  3 KB
  __shared__ float cd[64][CCAP];                        //  6 KB
  __shared__ int ccnt[64];
  __shared__ float m1row[64];
  __shared__ float z2s[64];
  __shared__ __align__(16) float c2l[1024];             //  4 KB

  const int tid = threadIdx.x, wg = blockIdx.x;
  const int wv = tid >> 6, ln = tid & 63;
  const int rl = ln & 15;           // row within wave's 16
  const int qk = ln >> 4;           // k-octet / code-quad selector
  const int rw = wv * 16 + rl;      // row local to WG
  const int rowg = wg * 64 + rw;    // global row

  // ---- c2 into LDS: every wave loads ALL of it (benign same-value race) ----
#pragma unroll
  for (int i = 0; i < 4; i++)
    ((float4*)c2l)[i * 64 + ln] = ((const float4*)c2n)[i * 64 + ln];
  // ---- per-wave candidate-count init (rows wv*16..wv*16+15 are wave-own) ---
  if (ln < 16) ccnt[wv * 16 + ln] = 0;

  // ---- build z hi-fragments in registers (one 16-row group) ----
  bf16x8 zH[8];
#pragma unroll
  for (int kc = 0; kc < 8; kc++) {
    const float4* p0 = (const float4*)(z + (size_t)rowg * DD + kc * 32 + qk * 8);
    const float4 a0 = p0[0], b0 = p0[1];
    zH[kc][0] = (short)bf16h(a0.x); zH[kc][1] = (short)bf16h(a0.y);
    zH[kc][2] = (short)bf16h(a0.z); zH[kc][3] = (short)bf16h(a0.w);
    zH[kc][4] = (short)bf16h(b0.x); zH[kc][5] = (short)bf16h(b0.y);
    zH[kc][6] = (short)bf16h(b0.z); zH[kc][7] = (short)bf16h(b0.w);
  }

  // ---- z2 (exact np AVX512 tree), wave-own 16 rows ----
  {
    const int gg = ln >> 4, l = ln & 15;
#pragma unroll 1
    for (int g4 = 0; g4 < 4; g4++) {
      const int rlcl = wv * 16 + g4 * 4 + gg;
      const float* q = z + (size_t)(wg * 64 + rlcl) * DD;
      float blk[2];
#pragma unroll
      for (int b = 0; b < 2; b++) {
        const float* qq = q + b * 128;
        const float s0 = FM(qq[l +   0], qq[l +   0]);
        const float s1 = FM(qq[l +  16], qq[l +  16]);
        const float s2 = FM(qq[l +  32], qq[l +  32]);
        const float s3 = FM(qq[l +  48], qq[l +  48]);
        const float s4 = FM(qq[l +  64], qq[l +  64]);
        const float s5 = FM(qq[l +  80], qq[l +  80]);
        const float s6 = FM(qq[l +  96], qq[l +  96]);
        const float s7 = FM(qq[l + 112], qq[l + 112]);
        float v = FA(FA(FA(s0, s1), FA(s2, s3)), FA(FA(s4, s5), FA(s6, s7)));
#pragma unroll
        for (int h = 8; h >= 1; h >>= 1) v = FA(v, __shfl_down(v, h, 16));
        blk[b] = v;
      }
      if (l == 0) z2s[rlcl] = FA(blk[0], blk[1]);
    }
  }

  const float z2v = z2s[rw];

  // ---- pipelined 64-tile screen ----
  float m1 = INFINITY;
  bf16x8 cur[8];
#pragma unroll
  for (int kc = 0; kc < 8; kc++)
    cur[kc] = *(const bf16x8*)(cbs + (size_t)kc * 512 + ln * 8);

#pragma unroll 1
  for (int t = 0; t < 64; t++) {
    // issue next tile's 8 independent loads (full iteration of slack)
    const int tn = (t < 63) ? t + 1 : 63;
    bf16x8 nxt[8];
#pragma unroll
    for (int kc = 0; kc < 8; kc++)
      nxt[kc] = *(const bf16x8*)(cbs + (size_t)tn * 4096 + kc * 512 + ln * 8);

    // two independent 4-deep MFMA chains over cur
    f32x4 accP = {0.f, 0.f, 0.f, 0.f}, accQ = accP;
#pragma unroll
    for (int kc = 0; kc < 4; kc++)
      accP = __builtin_amdgcn_mfma_f32_16x16x32_bf16(cur[kc], zH[kc], accP, 0, 0, 0);
#pragma unroll
    for (int kc = 4; kc < 8; kc++)
      accQ = __builtin_amdgcn_mfma_f32_16x16x32_bf16(cur[kc], zH[kc], accQ, 0, 0, 0);

    // fold: lane covers codes t*16 + qk*4 + r for row rl
    const float4 c2v4 = *(const float4*)&c2l[t * 16 + qk * 4];
    float dh[4];
#pragma unroll
    for (int r = 0; r < 4; r++) {
      const float c2v = r == 0 ? c2v4.x : r == 1 ? c2v4.y : r == 2 ? c2v4.z : c2v4.w;
      const float dot = accP[r] + accQ[r];
      dh[r] = z2v - 2.f * dot + c2v;
      m1 = fminf(m1, dh[r]);
    }
    m1 = fminf(m1, __shfl_xor(m1, 16));
    m1 = fminf(m1, __shfl_xor(m1, 32));
#pragma unroll
    for (int r = 0; r < 4; r++) {
      if (dh[r] <= m1 + MARG) {
        const int s = atomicAdd(&ccnt[rw], 1);
        if (s < CCAP) {
          ccode[rw][s] = (unsigned short)(t * 16 + qk * 4 + r);
          cd[rw][s] = dh[r];
        }
      }
    }
#pragma unroll
    for (int kc = 0; kc < 8; kc++) cur[kc] = nxt[kc];
  }

  if (qk == 0) m1row[rw] = m1;
  // (no barrier: all state is wave-own)

  // ---- finalize (wave-own rows: lanes 0..15 -> rows wv*16+ln) ----
  if (ln < 16) {
    const int rwl = wv * 16 + ln;
    const int row = wg * 64 + rwl;
    const float mf = m1row[rwl] + MARG;
    const int nc = ccnt[rwl];
    int best;
    if (nc > CCAP) {             // overflow (P~0): full exact np scan
      const float* zr = z + (size_t)row * DD;
      const float z2r = z2s[rwl];
      float db = INFINITY; best = 0;
      for (int c = 0; c < KC; c++) {
        const float* cr = cb + (size_t)c * DD;
        float dot = 0.f;
#pragma unroll 8
        for (int k = 0; k < DD; k++) dot = __fmaf_rn(zr[k], cr[k], dot);
        const float t1 = 2.0f * dot;
        const float d = FA(FA(z2r, -t1), c2l[c]);
        if (d < db) { db = d; best = c; }          // ascending c: first-min
      }
    } else {
      int kept = 0, kcode = 0;
      for (int s = 0; s < nc; s++)
        if (cd[rwl][s] <= mf) { kept++; kcode = ccode[rwl][s]; }
      if (kept == 1) best = kcode;
      else {
        const float* zr = z + (size_t)row * DD;
        const float z2r = z2s[rwl];
        float db = INFINITY; int bi = 0x7FFFFFFF;
        for (int s = 0; s < nc; s++) {
          if (cd[rwl][s] > mf) continue;
          const int c = ccode[rwl][s];
          const float* cr = cb + (size_t)c * DD;
          float dot = 0.f;
#pragma unroll 8
          for (int k = 0; k < DD; k++) dot = __fmaf_rn(zr[k], cr[k], dot);
          const float t1 = 2.0f * dot;
          const float d = FA(FA(z2r, -t1), c2l[c]);   // exact np-f32 d
          if (d < db || (d == db && c < bi)) { db = d; bi = c; }
        }
        best = bi;
      }
    }
    atomicAdd(&counts[best], 1);
    idxw[row] = best;
    out[IDX_OFF + row] = (float)best;
  }
}

// ---------------- K3: streaming epilogue (gather + outputs + loss) ----------
__global__ __launch_bounds__(256) void vqw_out(
    const float* __restrict__ z, const float* __restrict__ cb,
    const int* __restrict__ idxw, float* __restrict__ out,
    double* __restrict__ bss) {
  __shared__ double wred[4];
  const int wv = threadIdx.x >> 6, ln = threadIdx.x & 63;
  const int rowbase = (blockIdx.x * 4 + wv) * 16;

  float ss = 0.f;
#pragma unroll 1
  for (int g = 0; g < 16; g += 8) {
    float4 r4b[8], q4b[8];
#pragma unroll
    for (int u = 0; u < 8; u++) {
      const size_t zrow = (size_t)(rowbase + g + u) * DD;
      r4b[u] = ((const float4*)(z + zrow))[ln];
      q4b[u] = ((const float4*)(cb + (size_t)idxw[rowbase + g + u] * DD))[ln];
    }
#pragma unroll
    for (int u = 0; u < 8; u++) {
      const size_t zrow = (size_t)(rowbase + g + u) * DD;
      const float4 r4 = r4b[u];
      const float4 q4 = q4b[u];
      float4 stv, rsv; float dq;
      stv.x = r4.x + (q4.x - r4.x); rsv.x = r4.x - q4.x; dq = q4.x - r4.x; ss = fmaf(dq, dq, ss);
      stv.y = r4.y + (q4.y - r4.y); rsv.y = r4.y - q4.y; dq = q4.y - r4.y; ss = fmaf(dq, dq, ss);
      stv.z = r4.z + (q4.z - r4.z); rsv.z = r4.z - q4.z; dq = q4.z - r4.z; ss = fmaf(dq, dq, ss);
      stv.w = r4.w + (q4.w - r4.w); rsv.w = r4.w - q4.w; dq = q4.w - r4.w; ss = fmaf(dq, dq, ss);
      ((float4*)(out + ZQ_OFF  + zrow))[ln] = stv;
      ((float4*)(out + RES_OFF + zrow))[ln] = rsv;
    }
  }
  double dss = (double)ss;
  for (int o = 32; o; o >>= 1) dss += __shfl_down(dss, o, 64);
  if (ln == 0) wred[wv] = dss;
  __syncthreads();
  if (threadIdx.x == 0) bss[blockIdx.x] = wred[0] + wred[1] + wred[2] + wred[3];
}

// ---------------- K4: scalars (loss, perplexity) ----------------------------
__global__ void vqw_final(const int* __restrict__ counts,
                          const double* __restrict__ bss,
                          float* __restrict__ out) {
  __shared__ double red[256];
  const int t = threadIdx.x;
  double s = 0.0;
  for (int i = t; i < 2048; i += 256) s += bss[i];
  red[t] = s; __syncthreads();
  for (int s2 = 128; s2 > 0; s2 >>= 1) { if (t < s2) red[t] += red[t + s2]; __syncthreads(); }
  const double ssq = red[0];
  __syncthreads();
  double h = 0.0;
  for (int c = t; c < 1024; c += 256) {
    double p = (double)counts[c] / 131072.0;
    h += p * log(p + 1e-10);
  }
  red[t] = h; __syncthreads();
  for (int s2 = 128; s2 > 0; s2 >>= 1) { if (t < s2) red[t] += red[t + s2]; __syncthreads(); }
  if (t == 0) {
    out[LOSS_OFF] = (float)(0.25 * ssq / 33554432.0);
    out[PERP_OFF] = (float)exp(-red[0]);
  }
}

extern "C" void kernel_launch(void* const* d_in, const int* in_sizes, int n_in,
                              void* d_out, int out_size, void* d_ws, size_t ws_size,
                              hipStream_t stream) {
  // Bind inputs by SIZE: z has 33,554,432 elems, codebook 262,144.
  const float* z;
  const float* cb;
  if (in_sizes[0] == NR * DD) { z = (const float*)d_in[0]; cb = (const float*)d_in[1]; }
  else                        { cb = (const float*)d_in[0]; z = (const float*)d_in[1]; }

  float* out = (float*)d_out;
  char* ws = (char*)d_ws;
  int*            counts = (int*)(ws + WS_CNT);
  float*          c2n    = (float*)(ws + WS_C2N);
  int*            idxw   = (int*)(ws + WS_IDX);
  double*         bssp   = (double*)(ws + WS_BSS);
  unsigned short* cbs    = (unsigned short*)(ws + WS_CBS);

  hipMemsetAsync(counts, 0, 4096, stream);
  vqw_c2<<<4, 256, 0, stream>>>(cb, c2n);
  vqw_cbsplit<<<128, 256, 0, stream>>>(cb, cbs);
  vqw_main<<<NR / 64, 256, 0, stream>>>(z, cb, cbs, c2n, out, counts, idxw);
  vqw_out<<<2048, 256, 0, stream>>>(z, cb, idxw, out, bssp);
  vqw_final<<<1, 256, 0, stream>>>(counts, bssp, out);
}

// Round 23
// 340.087 us; speedup vs baseline: 1.1862x; 1.0864x over previous
//
#include <hip/hip_runtime.h>
#include <math.h>

#define NR 131072
#define KC 1024
#define DD 256

// d_out element offsets (float32 elements)
#define ZQ_OFF  0
#define RES_OFF 33554432
#define IDX_OFF 67108864
#define LOSS_OFF 67239936
#define PERP_OFF 67239937

// ws byte offsets (total ~1.06 MB)
#define WS_CNT 0          // int[1024]
#define WS_C2N 4096       // float[1024]
#define WS_IDX 8192       // int[131072] = 512KB
#define WS_BSS 532480     // double[2048]
#define WS_CBS 548864     // ushort cbs hi-only: 64 tiles x 8KB = 512KB

#define MARG 5e-4f
#define CCAP 24

#define FM(x,y) __fmul_rn((x),(y))
#define FA(x,y) __fadd_rn((x),(y))

typedef __attribute__((ext_vector_type(8))) short bf16x8;
typedef __attribute__((ext_vector_type(4))) float f32x4;

static __device__ __forceinline__ unsigned short bf16h(float f) {
  unsigned int u = __float_as_uint(f);
  u += 0x7FFFu + ((u >> 16) & 1u);
  return (unsigned short)(u >> 16);
}

// ---- numpy f32 pairwise sum-of-squares, one 128-block (AVX512 tree) --------
static __device__ __forceinline__ float np_sumsq128(const float* __restrict__ q) {
  float lane[16];
#pragma unroll
  for (int l = 0; l < 16; l++) {
    float s0 = FM(q[l +   0], q[l +   0]);
    float s1 = FM(q[l +  16], q[l +  16]);
    float s2 = FM(q[l +  32], q[l +  32]);
    float s3 = FM(q[l +  48], q[l +  48]);
    float s4 = FM(q[l +  64], q[l +  64]);
    float s5 = FM(q[l +  80], q[l +  80]);
    float s6 = FM(q[l +  96], q[l +  96]);
    float s7 = FM(q[l + 112], q[l + 112]);
    lane[l] = FA(FA(FA(s0, s1), FA(s2, s3)), FA(FA(s4, s5), FA(s6, s7)));
  }
#pragma unroll
  for (int h = 8; h >= 1; h >>= 1)
#pragma unroll
    for (int l = 0; l < 8; l++)
      if (l < h) lane[l] = FA(lane[l], lane[l + h]);
  return lane[0];
}

static __device__ __forceinline__ float np_sumsq256(const float* __restrict__ p) {
  return FA(np_sumsq128(p), np_sumsq128(p + 128));
}

// ---------------- K1a: codebook c2 (numpy-replica f32) ----------------------
__global__ void vqx_c2(const float* __restrict__ cb, float* __restrict__ c2n) {
  const int code = blockIdx.x * 256 + threadIdx.x;
  if (code < KC) c2n[code] = np_sumsq256(cb + (size_t)code * DD);
}

// ---------------- K1b: codebook bf16 hi split, MFMA-granule layout ----------
__global__ void vqx_cbsplit(const float* __restrict__ cb,
                            unsigned short* __restrict__ cbs) {
  const int g  = blockIdx.x * 256 + threadIdx.x;   // 0..32767
  const int t  = g >> 9;
  const int gi = g & 511;
  const int kc = gi >> 6, q = (gi >> 4) & 3, c = gi & 15;
  const float* src = cb + (size_t)(t * 16 + c) * DD + kc * 32 + q * 8;
  unsigned int w[4];
#pragma unroll
  for (int p = 0; p < 4; p++)
    w[p] = (unsigned int)bf16h(src[p * 2]) |
           ((unsigned int)bf16h(src[p * 2 + 1]) << 16);
  *(uint4*)(cbs + (size_t)g * 8) = make_uint4(w[0], w[1], w[2], w[3]);
}

// ---------------- K2: pinned-pipeline screen + finalize ---------------------
// 128 rows/WG (1024 WGs), 4 waves, TWO 16-row groups/wave (halves L2 cbs
// traffic vs G=1: 60us floor). launch_bounds(256,2): 256-VGPR budget so
// zH(64)+cur(32)+nxt(32)+acc(16)+temps fit -> no spill, no load-sinking.
// sched_barrier(0) pins the 8 next-tile loads BEFORE the MFMA block: each
// load gets a full iteration of slack (MLP ~8/wave). MFMA chains 4-deep.
__global__ __launch_bounds__(256, 2) void vqx_main(
    const float* __restrict__ z, const float* __restrict__ cb,
    const unsigned short* __restrict__ cbs,
    const float* __restrict__ c2n,
    float* __restrict__ out, int* __restrict__ counts,
    int* __restrict__ idxw) {
  __shared__ unsigned short ccode[128][CCAP];           //  6 KB
  __shared__ float cd[128][CCAP];                       // 12 KB
  __shared__ int ccnt[128];
  __shared__ float m1row[128];
  __shared__ float z2s[128];
  __shared__ __align__(16) float c2l[1024];             //  4 KB

  const int tid = threadIdx.x, wg = blockIdx.x;
  const int wv = tid >> 6, ln = tid & 63;
  const int rl = ln & 15;           // row within group
  const int qk = ln >> 4;           // k-octet / code-quad selector
  const int rowg0 = wg * 128 + wv * 32 + rl;      // group-0 global row

  // ---- c2 into LDS: every wave loads ALL of it (benign same-value race) ----
#pragma unroll
  for (int i = 0; i < 4; i++)
    ((float4*)c2l)[i * 64 + ln] = ((const float4*)c2n)[i * 64 + ln];
  // ---- per-wave candidate-count init ----
  if (ln < 32) ccnt[wv * 32 + ln] = 0;

  // ---- build z hi-fragments in registers for both row-groups ----
  bf16x8 zH0[8], zH1[8];
#pragma unroll
  for (int kc = 0; kc < 8; kc++) {
    const float4* p0 = (const float4*)(z + (size_t)rowg0 * DD + kc * 32 + qk * 8);
    const float4* p1 = (const float4*)(z + (size_t)(rowg0 + 16) * DD + kc * 32 + qk * 8);
    const float4 a0 = p0[0], b0 = p0[1];
    const float4 a1 = p1[0], b1 = p1[1];
    zH0[kc][0] = (short)bf16h(a0.x); zH0[kc][1] = (short)bf16h(a0.y);
    zH0[kc][2] = (short)bf16h(a0.z); zH0[kc][3] = (short)bf16h(a0.w);
    zH0[kc][4] = (short)bf16h(b0.x); zH0[kc][5] = (short)bf16h(b0.y);
    zH0[kc][6] = (short)bf16h(b0.z); zH0[kc][7] = (short)bf16h(b0.w);
    zH1[kc][0] = (short)bf16h(a1.x); zH1[kc][1] = (short)bf16h(a1.y);
    zH1[kc][2] = (short)bf16h(a1.z); zH1[kc][3] = (short)bf16h(a1.w);
    zH1[kc][4] = (short)bf16h(b1.x); zH1[kc][5] = (short)bf16h(b1.y);
    zH1[kc][6] = (short)bf16h(b1.z); zH1[kc][7] = (short)bf16h(b1.w);
  }

  // ---- z2 (exact np AVX512 tree), wave-own rows only ----
  {
    const int gg = ln >> 4, l = ln & 15;
#pragma unroll 1
    for (int g4 = 0; g4 < 8; g4++) {
      const int rlcl = wv * 32 + g4 * 4 + gg;
      const float* q = z + (size_t)(wg * 128 + rlcl) * DD;
      float blk[2];
#pragma unroll
      for (int b = 0; b < 2; b++) {
        const float* qq = q + b * 128;
        const float s0 = FM(qq[l +   0], qq[l +   0]);
        const float s1 = FM(qq[l +  16], qq[l +  16]);
        const float s2 = FM(qq[l +  32], qq[l +  32]);
        const float s3 = FM(qq[l +  48], qq[l +  48]);
        const float s4 = FM(qq[l +  64], qq[l +  64]);
        const float s5 = FM(qq[l +  80], qq[l +  80]);
        const float s6 = FM(qq[l +  96], qq[l +  96]);
        const float s7 = FM(qq[l + 112], qq[l + 112]);
        float v = FA(FA(FA(s0, s1), FA(s2, s3)), FA(FA(s4, s5), FA(s6, s7)));
#pragma unroll
        for (int h = 8; h >= 1; h >>= 1) v = FA(v, __shfl_down(v, h, 16));
        blk[b] = v;
      }
      if (l == 0) z2s[rlcl] = FA(blk[0], blk[1]);
    }
  }

  const float z2v0 = z2s[wv * 32 + rl];
  const float z2v1 = z2s[wv * 32 + rl + 16];
  const int rw0 = wv * 32 + rl;

  float m10 = INFINITY, m11 = INFINITY;
  bf16x8 cur[8];
#pragma unroll
  for (int kc = 0; kc < 8; kc++)
    cur[kc] = *(const bf16x8*)(cbs + (size_t)kc * 512 + ln * 8);

#pragma unroll 1
  for (int t = 0; t < 64; t++) {
    // ---- issue next tile's 8 independent loads, PINNED before compute ----
    const int tn = (t < 63) ? t + 1 : 63;
    bf16x8 nxt[8];
#pragma unroll
    for (int kc = 0; kc < 8; kc++)
      nxt[kc] = *(const bf16x8*)(cbs + (size_t)tn * 4096 + kc * 512 + ln * 8);
    __builtin_amdgcn_sched_barrier(0);   // loads stay issued before MFMAs

    // ---- four independent 4-deep MFMA chains over cur ----
    f32x4 aP0 = {0.f, 0.f, 0.f, 0.f}, aQ0 = aP0, aP1 = aP0, aQ1 = aP0;
#pragma unroll
    for (int kc = 0; kc < 4; kc++) {
      aP0 = __builtin_amdgcn_mfma_f32_16x16x32_bf16(cur[kc], zH0[kc], aP0, 0, 0, 0);
      aP1 = __builtin_amdgcn_mfma_f32_16x16x32_bf16(cur[kc], zH1[kc], aP1, 0, 0, 0);
    }
#pragma unroll
    for (int kc = 4; kc < 8; kc++) {
      aQ0 = __builtin_amdgcn_mfma_f32_16x16x32_bf16(cur[kc], zH0[kc], aQ0, 0, 0, 0);
      aQ1 = __builtin_amdgcn_mfma_f32_16x16x32_bf16(cur[kc], zH1[kc], aQ1, 0, 0, 0);
    }
    __builtin_amdgcn_sched_barrier(0);   // fold stays after MFMAs

    // ---- fold: lane covers codes t*16 + qk*4 + r, rows (group0, group1) ----
    const float4 c2v4 = *(const float4*)&c2l[t * 16 + qk * 4];
    float dh0[4], dh1[4];
#pragma unroll
    for (int r = 0; r < 4; r++) {
      const float c2v = r == 0 ? c2v4.x : r == 1 ? c2v4.y : r == 2 ? c2v4.z : c2v4.w;
      dh0[r] = z2v0 - 2.f * (aP0[r] + aQ0[r]) + c2v;
      dh1[r] = z2v1 - 2.f * (aP1[r] + aQ1[r]) + c2v;
      m10 = fminf(m10, dh0[r]);
      m11 = fminf(m11, dh1[r]);
    }
    m10 = fminf(m10, __shfl_xor(m10, 16));
    m10 = fminf(m10, __shfl_xor(m10, 32));
    m11 = fminf(m11, __shfl_xor(m11, 16));
    m11 = fminf(m11, __shfl_xor(m11, 32));
#pragma unroll
    for (int r = 0; r < 4; r++) {
      if (dh0[r] <= m10 + MARG) {
        const int s = atomicAdd(&ccnt[rw0], 1);
        if (s < CCAP) {
          ccode[rw0][s] = (unsigned short)(t * 16 + qk * 4 + r);
          cd[rw0][s] = dh0[r];
        }
      }
      if (dh1[r] <= m11 + MARG) {
        const int s = atomicAdd(&ccnt[rw0 + 16], 1);
        if (s < CCAP) {
          ccode[rw0 + 16][s] = (unsigned short)(t * 16 + qk * 4 + r);
          cd[rw0 + 16][s] = dh1[r];
        }
      }
    }
#pragma unroll
    for (int kc = 0; kc < 8; kc++) cur[kc] = nxt[kc];
  }

  if (qk == 0) { m1row[rw0] = m10; m1row[rw0 + 16] = m11; }
  // (no barrier: all state is wave-own)

  // ---- finalize (wave-own rows: lanes 0..31 -> rows wv*32+ln) ----
  if (ln < 32) {
    const int rwl = wv * 32 + ln;
    const int row = wg * 128 + rwl;
    const float mf = m1row[rwl] + MARG;
    const int nc = ccnt[rwl];
    int best;
    if (nc > CCAP) {             // overflow (P~0): full exact np scan
      const float* zr = z + (size_t)row * DD;
      const float z2r = z2s[rwl];
      float db = INFINITY; best = 0;
      for (int c = 0; c < KC; c++) {
        const float* cr = cb + (size_t)c * DD;
        float dot = 0.f;
#pragma unroll 8
        for (int k = 0; k < DD; k++) dot = __fmaf_rn(zr[k], cr[k], dot);
        const float t1 = 2.0f * dot;
        const float d = FA(FA(z2r, -t1), c2l[c]);
        if (d < db) { db = d; best = c; }          // ascending c: first-min
      }
    } else {
      int kept = 0, kcode = 0;
      for (int s = 0; s < nc; s++)
        if (cd[rwl][s] <= mf) { kept++; kcode = ccode[rwl][s]; }
      if (kept == 1) best = kcode;
      else {
        const float* zr = z + (size_t)row * DD;
        const float z2r = z2s[rwl];
        float db = INFINITY; int bi = 0x7FFFFFFF;
        for (int s = 0; s < nc; s++) {
          if (cd[rwl][s] > mf) continue;
          const int c = ccode[rwl][s];
          const float* cr = cb + (size_t)c * DD;
          float dot = 0.f;
#pragma unroll 8
          for (int k = 0; k < DD; k++) dot = __fmaf_rn(zr[k], cr[k], dot);
          const float t1 = 2.0f * dot;
          const float d = FA(FA(z2r, -t1), c2l[c]);   // exact np-f32 d
          if (d < db || (d == db && c < bi)) { db = d; bi = c; }
        }
        best = bi;
      }
    }
    atomicAdd(&counts[best], 1);
    idxw[row] = best;
    out[IDX_OFF + row] = (float)best;
  }
}

// ---------------- K3: streaming epilogue (gather + outputs + loss) ----------
__global__ __launch_bounds__(256) void vqx_out(
    const float* __restrict__ z, const float* __restrict__ cb,
    const int* __restrict__ idxw, float* __restrict__ out,
    double* __restrict__ bss) {
  __shared__ double wred[4];
  const int wv = threadIdx.x >> 6, ln = threadIdx.x & 63;
  const int rowbase = (blockIdx.x * 4 + wv) * 16;

  float ss = 0.f;
#pragma unroll 1
  for (int g = 0; g < 16; g += 8) {
    float4 r4b[8], q4b[8];
#pragma unroll
    for (int u = 0; u < 8; u++) {
      const size_t zrow = (size_t)(rowbase + g + u) * DD;
      r4b[u] = ((const float4*)(z + zrow))[ln];
      q4b[u] = ((const float4*)(cb + (size_t)idxw[rowbase + g + u] * DD))[ln];
    }
#pragma unroll
    for (int u = 0; u < 8; u++) {
      const size_t zrow = (size_t)(rowbase + g + u) * DD;
      const float4 r4 = r4b[u];
      const float4 q4 = q4b[u];
      float4 stv, rsv; float dq;
      stv.x = r4.x + (q4.x - r4.x); rsv.x = r4.x - q4.x; dq = q4.x - r4.x; ss = fmaf(dq, dq, ss);
      stv.y = r4.y + (q4.y - r4.y); rsv.y = r4.y - q4.y; dq = q4.y - r4.y; ss = fmaf(dq, dq, ss);
      stv.z = r4.z + (q4.z - r4.z); rsv.z = r4.z - q4.z; dq = q4.z - r4.z; ss = fmaf(dq, dq, ss);
      stv.w = r4.w + (q4.w - r4.w); rsv.w = r4.w - q4.w; dq = q4.w - r4.w; ss = fmaf(dq, dq, ss);
      ((float4*)(out + ZQ_OFF  + zrow))[ln] = stv;
      ((float4*)(out + RES_OFF + zrow))[ln] = rsv;
    }
  }
  double dss = (double)ss;
  for (int o = 32; o; o >>= 1) dss += __shfl_down(dss, o, 64);
  if (ln == 0) wred[wv] = dss;
  __syncthreads();
  if (threadIdx.x == 0) bss[blockIdx.x] = wred[0] + wred[1] + wred[2] + wred[3];
}

// ---------------- K4: scalars (loss, perplexity) ----------------------------
__global__ void vqx_final(const int* __restrict__ counts,
                          const double* __restrict__ bss,
                          float* __restrict__ out) {
  __shared__ double red[256];
  const int t = threadIdx.x;
  double s = 0.0;
  for (int i = t; i < 2048; i += 256) s += bss[i];
  red[t] = s; __syncthreads();
  for (int s2 = 128; s2 > 0; s2 >>= 1) { if (t < s2) red[t] += red[t + s2]; __syncthreads(); }
  const double ssq = red[0];
  __syncthreads();
  double h = 0.0;
  for (int c = t; c < 1024; c += 256) {
    double p = (double)counts[c] / 131072.0;
    h += p * log(p + 1e-10);
  }
  red[t] = h; __syncthreads();
  for (int s2 = 128; s2 > 0; s2 >>= 1) { if (t < s2) red[t] += red[t + s2]; __syncthreads(); }
  if (t == 0) {
    out[LOSS_OFF] = (float)(0.25 * ssq / 33554432.0);
    out[PERP_OFF] = (float)exp(-red[0]);
  }
}

extern "C" void kernel_launch(void* const* d_in, const int* in_sizes, int n_in,
                              void* d_out, int out_size, void* d_ws, size_t ws_size,
                              hipStream_t stream) {
  // Bind inputs by SIZE: z has 33,554,432 elems, codebook 262,144.
  const float* z;
  const float* cb;
  if (in_sizes[0] == NR * DD) { z = (const float*)d_in[0]; cb = (const float*)d_in[1]; }
  else                        { cb = (const float*)d_in[0]; z = (const float*)d_in[1]; }

  float* out = (float*)d_out;
  char* ws = (char*)d_ws;
  int*            counts = (int*)(ws + WS_CNT);
  float*          c2n    = (float*)(ws + WS_C2N);
  int*            idxw   = (int*)(ws + WS_IDX);
  double*         bssp   = (double*)(ws + WS_BSS);
  unsigned short* cbs    = (unsigned short*)(ws + WS_CBS);

  hipMemsetAsync(counts, 0, 4096, stream);
  vqx_c2<<<4, 256, 0, stream>>>(cb, c2n);
  vqx_cbsplit<<<128, 256, 0, stream>>>(cb, cbs);
  vqx_main<<<NR / 128, 256, 0, stream>>>(z, cb, cbs, c2n, out, counts, idxw);
  vqx_out<<<2048, 256, 0, stream>>>(z, cb, idxw, out, bssp);
  vqx_final<<<1, 256, 0, stream>>>(counts, bssp, out);
}

// Round 24
// 300.662 us; speedup vs baseline: 1.3417x; 1.1311x over previous
//
#include <hip/hip_runtime.h>
#include <math.h>

#define NR 131072
#define KC 1024
#define DD 256

// d_out element offsets (float32 elements)
#define ZQ_OFF  0
#define RES_OFF 33554432
#define IDX_OFF 67108864
#define LOSS_OFF 67239936
#define PERP_OFF 67239937

// ws byte offsets (total ~536 KB)
#define WS_CNT 0          // int[1024]
#define WS_C2N 4096       // float[1024]
#define WS_BSS 8192       // double[1024]
#define WS_CBS 16384      // ushort cbs hi-only: 64 tiles x 8KB = 512KB

#define MARG 5e-4f
#define CCAP 32

#define FM(x,y) __fmul_rn((x),(y))
#define FA(x,y) __fadd_rn((x),(y))

typedef __attribute__((ext_vector_type(8))) short bf16x8;
typedef __attribute__((ext_vector_type(4))) float f32x4;

static __device__ __forceinline__ unsigned short bf16h(float f) {
  unsigned int u = __float_as_uint(f);
  u += 0x7FFFu + ((u >> 16) & 1u);
  return (unsigned short)(u >> 16);
}

// ---- numpy f32 pairwise sum-of-squares, one 128-block (AVX512 tree) --------
static __device__ __forceinline__ float np_sumsq128(const float* __restrict__ q) {
  float lane[16];
#pragma unroll
  for (int l = 0; l < 16; l++) {
    float s0 = FM(q[l +   0], q[l +   0]);
    float s1 = FM(q[l +  16], q[l +  16]);
    float s2 = FM(q[l +  32], q[l +  32]);
    float s3 = FM(q[l +  48], q[l +  48]);
    float s4 = FM(q[l +  64], q[l +  64]);
    float s5 = FM(q[l +  80], q[l +  80]);
    float s6 = FM(q[l +  96], q[l +  96]);
    float s7 = FM(q[l + 112], q[l + 112]);
    lane[l] = FA(FA(FA(s0, s1), FA(s2, s3)), FA(FA(s4, s5), FA(s6, s7)));
  }
#pragma unroll
  for (int h = 8; h >= 1; h >>= 1)
#pragma unroll
    for (int l = 0; l < 8; l++)
      if (l < h) lane[l] = FA(lane[l], lane[l + h]);
  return lane[0];
}

static __device__ __forceinline__ float np_sumsq256(const float* __restrict__ p) {
  return FA(np_sumsq128(p), np_sumsq128(p + 128));
}

// ---------------- K1a: codebook c2 (numpy-replica f32) ----------------------
__global__ void vqz_c2(const float* __restrict__ cb, float* __restrict__ c2n) {
  const int code = blockIdx.x * 256 + threadIdx.x;
  if (code < KC) c2n[code] = np_sumsq256(cb + (size_t)code * DD);
}

// ---------------- K1b: codebook bf16 hi split, MFMA-granule layout ----------
__global__ void vqz_cbsplit(const float* __restrict__ cb,
                            unsigned short* __restrict__ cbs) {
  const int g  = blockIdx.x * 256 + threadIdx.x;   // 0..32767
  const int t  = g >> 9;
  const int gi = g & 511;
  const int kc = gi >> 6, q = (gi >> 4) & 3, c = gi & 15;
  const float* src = cb + (size_t)(t * 16 + c) * DD + kc * 32 + q * 8;
  unsigned int w[4];
#pragma unroll
  for (int p = 0; p < 4; p++)
    w[p] = (unsigned int)bf16h(src[p * 2]) |
           ((unsigned int)bf16h(src[p * 2 + 1]) << 16);
  *(uint4*)(cbs + (size_t)g * 8) = make_uint4(w[0], w[1], w[2], w[3]);
}

// ---------------- K2: fused screen + rescore + outputs (staggered tiles) ----
// r18's proven wave-decoupled fused kernel + STAGGERED CIRCULAR TILE ORDER:
// wave (wg,wv) sweeps tiles starting at (wg*4+wv)&63, so resident waves hit
// 64 DIFFERENT cbs tiles at any instant -> L2 same-line contention removed.
// Correctness: candidate set under any order is a superset of
// {d <= final_min+MARG}; finalize filters with final min; rescore lex-min is
// order-independent; CCAP 24->32 for the higher random-order append count.
__global__ __launch_bounds__(256, 4) void vqz_main(
    const float* __restrict__ z, const float* __restrict__ cb,
    const unsigned short* __restrict__ cbs,
    const float* __restrict__ c2n,
    float* __restrict__ out, int* __restrict__ counts,
    double* __restrict__ bss) {
  __shared__ unsigned short ccode[128][CCAP];           //  8 KB
  __shared__ float cd[128][CCAP];                       // 16 KB
  __shared__ int ccnt[128];
  __shared__ float m1row[128];
  __shared__ float z2s[128];
  __shared__ int rowidx[128];
  __shared__ __align__(16) float c2l[1024];             //  4 KB
  __shared__ double wred[4];

  const int tid = threadIdx.x, wg = blockIdx.x;
  const int wv = tid >> 6, ln = tid & 63;
  const int rl = ln & 15;           // row within group
  const int qk = ln >> 4;           // k-octet / code-quad selector
  const int rowg0 = wg * 128 + wv * 32 + rl;      // group-0 global row

  // ---- c2 into LDS: every wave loads ALL of it (benign same-value race) ----
#pragma unroll
  for (int i = 0; i < 4; i++)
    ((float4*)c2l)[i * 64 + ln] = ((const float4*)c2n)[i * 64 + ln];
  // ---- per-wave candidate-count init ----
  if (ln < 32) ccnt[wv * 32 + ln] = 0;

  // ---- build z hi-fragments in registers for both row-groups ----
  bf16x8 zH0[8], zH1[8];
#pragma unroll
  for (int kc = 0; kc < 8; kc++) {
    const float4* p0 = (const float4*)(z + (size_t)rowg0 * DD + kc * 32 + qk * 8);
    const float4* p1 = (const float4*)(z + (size_t)(rowg0 + 16) * DD + kc * 32 + qk * 8);
    const float4 a0 = p0[0], b0 = p0[1];
    const float4 a1 = p1[0], b1 = p1[1];
    zH0[kc][0] = (short)bf16h(a0.x); zH0[kc][1] = (short)bf16h(a0.y);
    zH0[kc][2] = (short)bf16h(a0.z); zH0[kc][3] = (short)bf16h(a0.w);
    zH0[kc][4] = (short)bf16h(b0.x); zH0[kc][5] = (short)bf16h(b0.y);
    zH0[kc][6] = (short)bf16h(b0.z); zH0[kc][7] = (short)bf16h(b0.w);
    zH1[kc][0] = (short)bf16h(a1.x); zH1[kc][1] = (short)bf16h(a1.y);
    zH1[kc][2] = (short)bf16h(a1.z); zH1[kc][3] = (short)bf16h(a1.w);
    zH1[kc][4] = (short)bf16h(b1.x); zH1[kc][5] = (short)bf16h(b1.y);
    zH1[kc][6] = (short)bf16h(b1.z); zH1[kc][7] = (short)bf16h(b1.w);
  }

  // ---- z2 (exact np AVX512 tree), wave-own rows only ----
  {
    const int gg = ln >> 4, l = ln & 15;
#pragma unroll 1
    for (int g4 = 0; g4 < 8; g4++) {
      const int rlcl = wv * 32 + g4 * 4 + gg;
      const float* q = z + (size_t)(wg * 128 + rlcl) * DD;
      float blk[2];
#pragma unroll
      for (int b = 0; b < 2; b++) {
        const float* qq = q + b * 128;
        const float s0 = FM(qq[l +   0], qq[l +   0]);
        const float s1 = FM(qq[l +  16], qq[l +  16]);
        const float s2 = FM(qq[l +  32], qq[l +  32]);
        const float s3 = FM(qq[l +  48], qq[l +  48]);
        const float s4 = FM(qq[l +  64], qq[l +  64]);
        const float s5 = FM(qq[l +  80], qq[l +  80]);
        const float s6 = FM(qq[l +  96], qq[l +  96]);
        const float s7 = FM(qq[l + 112], qq[l + 112]);
        float v = FA(FA(FA(s0, s1), FA(s2, s3)), FA(FA(s4, s5), FA(s6, s7)));
#pragma unroll
        for (int h = 8; h >= 1; h >>= 1) v = FA(v, __shfl_down(v, h, 16));
        blk[b] = v;
      }
      if (l == 0) z2s[rlcl] = FA(blk[0], blk[1]);
    }
  }

  const float z2v0 = z2s[wv * 32 + rl];
  const float z2v1 = z2s[wv * 32 + rl + 16];
  const int rw0 = wv * 32 + rl;
  const int t0 = (wg * 4 + wv) & 63;      // per-wave staggered start tile

  float m10 = INFINITY, m11 = INFINITY;
#pragma unroll 2
  for (int i = 0; i < 64; i++) {
    const int t = (t0 + i) & 63;
    // direct global->register A-fragments (L2-resident cbs, coalesced 1KB/load)
    bf16x8 aH[8];
#pragma unroll
    for (int kc = 0; kc < 8; kc++)
      aH[kc] = *(const bf16x8*)(cbs + (size_t)t * 4096 + kc * 512 + ln * 8);

    f32x4 accA = {0.f, 0.f, 0.f, 0.f}, accB = accA;
#pragma unroll
    for (int kc = 0; kc < 8; kc++) {
      accA = __builtin_amdgcn_mfma_f32_16x16x32_bf16(aH[kc], zH0[kc], accA, 0, 0, 0);
      accB = __builtin_amdgcn_mfma_f32_16x16x32_bf16(aH[kc], zH1[kc], accB, 0, 0, 0);
    }
    // fold: lane covers codes t*16 + qk*4 + r, rows (group0, group1)
    const float4 c2v4 = *(const float4*)&c2l[t * 16 + qk * 4];
    float dh0[4], dh1[4];
#pragma unroll
    for (int r = 0; r < 4; r++) {
      const float c2v = r == 0 ? c2v4.x : r == 1 ? c2v4.y : r == 2 ? c2v4.z : c2v4.w;
      dh0[r] = z2v0 - 2.f * accA[r] + c2v;
      dh1[r] = z2v1 - 2.f * accB[r] + c2v;
      m10 = fminf(m10, dh0[r]);
      m11 = fminf(m11, dh1[r]);
    }
    m10 = fminf(m10, __shfl_xor(m10, 16));
    m10 = fminf(m10, __shfl_xor(m10, 32));
    m11 = fminf(m11, __shfl_xor(m11, 16));
    m11 = fminf(m11, __shfl_xor(m11, 32));
#pragma unroll
    for (int r = 0; r < 4; r++) {
      if (dh0[r] <= m10 + MARG) {
        const int s = atomicAdd(&ccnt[rw0], 1);
        if (s < CCAP) {
          ccode[rw0][s] = (unsigned short)(t * 16 + qk * 4 + r);
          cd[rw0][s] = dh0[r];
        }
      }
      if (dh1[r] <= m11 + MARG) {
        const int s = atomicAdd(&ccnt[rw0 + 16], 1);
        if (s < CCAP) {
          ccode[rw0 + 16][s] = (unsigned short)(t * 16 + qk * 4 + r);
          cd[rw0 + 16][s] = dh1[r];
        }
      }
    }
  }

  if (qk == 0) { m1row[rw0] = m10; m1row[rw0 + 16] = m11; }
  // (no barrier: all intermediate state is wave-own)

  // ---- finalize (wave-own rows: lanes 0..31 -> rows wv*32+ln) ----
  if (ln < 32) {
    const int rwl = wv * 32 + ln;
    const int row = wg * 128 + rwl;
    const float mf = m1row[rwl] + MARG;
    const int nc = ccnt[rwl];
    int best;
    if (nc > CCAP) {             // overflow (rare): full exact np scan
      const float* zr = z + (size_t)row * DD;
      const float z2r = z2s[rwl];
      float db = INFINITY; best = 0;
      for (int c = 0; c < KC; c++) {
        const float* cr = cb + (size_t)c * DD;
        float dot = 0.f;
#pragma unroll 8
        for (int k = 0; k < DD; k++) dot = __fmaf_rn(zr[k], cr[k], dot);
        const float t1 = 2.0f * dot;
        const float d = FA(FA(z2r, -t1), c2l[c]);
        if (d < db) { db = d; best = c; }          // ascending c: first-min
      }
    } else {
      int kept = 0, kcode = 0;
      for (int s = 0; s < nc; s++)
        if (cd[rwl][s] <= mf) { kept++; kcode = ccode[rwl][s]; }
      if (kept == 1) best = kcode;
      else {
        const float* zr = z + (size_t)row * DD;
        const float z2r = z2s[rwl];
        float db = INFINITY; int bi = 0x7FFFFFFF;
        for (int s = 0; s < nc; s++) {
          if (cd[rwl][s] > mf) continue;
          const int c = ccode[rwl][s];
          const float* cr = cb + (size_t)c * DD;
          float dot = 0.f;
#pragma unroll 8
          for (int k = 0; k < DD; k++) dot = __fmaf_rn(zr[k], cr[k], dot);
          const float t1 = 2.0f * dot;
          const float d = FA(FA(z2r, -t1), c2l[c]);   // exact np-f32 d
          if (d < db || (d == db && c < bi)) { db = d; bi = c; }
        }
        best = bi;
      }
    }
    rowidx[rwl] = best;
    atomicAdd(&counts[best], 1);
    out[IDX_OFF + row] = (float)best;
  }
  // (no barrier: rowidx for this wave's rows written by this wave)

  // ---- gather + zq_st / residual: one wave per row, 8-row batches ----
  float ss = 0.f;
#pragma unroll 1
  for (int g = 0; g < 32; g += 8) {
    float4 r4b[8], q4b[8];
#pragma unroll
    for (int u = 0; u < 8; u++) {
      const int rlcl = wv * 32 + g + u;
      const size_t zrow = (size_t)(wg * 128 + rlcl) * DD;
      r4b[u] = ((const float4*)(z + zrow))[ln];
      q4b[u] = ((const float4*)(cb + (size_t)rowidx[rlcl] * DD))[ln];
    }
#pragma unroll
    for (int u = 0; u < 8; u++) {
      const int rlcl = wv * 32 + g + u;
      const size_t zrow = (size_t)(wg * 128 + rlcl) * DD;
      const float4 r4 = r4b[u];
      const float4 q4 = q4b[u];
      float4 stv, rsv; float dq;
      stv.x = r4.x + (q4.x - r4.x); rsv.x = r4.x - q4.x; dq = q4.x - r4.x; ss = fmaf(dq, dq, ss);
      stv.y = r4.y + (q4.y - r4.y); rsv.y = r4.y - q4.y; dq = q4.y - r4.y; ss = fmaf(dq, dq, ss);
      stv.z = r4.z + (q4.z - r4.z); rsv.z = r4.z - q4.z; dq = q4.z - r4.z; ss = fmaf(dq, dq, ss);
      stv.w = r4.w + (q4.w - r4.w); rsv.w = r4.w - q4.w; dq = q4.w - r4.w; ss = fmaf(dq, dq, ss);
      ((float4*)(out + ZQ_OFF  + zrow))[ln] = stv;
      ((float4*)(out + RES_OFF + zrow))[ln] = rsv;
    }
  }
  double dss = (double)ss;
  for (int o = 32; o; o >>= 1) dss += __shfl_down(dss, o, 64);
  if (ln == 0) wred[wv] = dss;
  __syncthreads();                 // ONLY cross-wave sync: loss reduction
  if (tid == 0) bss[wg] = wred[0] + wred[1] + wred[2] + wred[3];
}

// ---------------- K3: scalars (loss, perplexity) ----------------------------
__global__ void vqz_final(const int* __restrict__ counts,
                          const double* __restrict__ bss,
                          float* __restrict__ out) {
  __shared__ double red[256];
  const int t = threadIdx.x;
  double s = 0.0;
  for (int i = t; i < 1024; i += 256) s += bss[i];
  red[t] = s; __syncthreads();
  for (int s2 = 128; s2 > 0; s2 >>= 1) { if (t < s2) red[t] += red[t + s2]; __syncthreads(); }
  const double ssq = red[0];
  __syncthreads();
  double h = 0.0;
  for (int c = t; c < 1024; c += 256) {
    double p = (double)counts[c] / 131072.0;
    h += p * log(p + 1e-10);
  }
  red[t] = h; __syncthreads();
  for (int s2 = 128; s2 > 0; s2 >>= 1) { if (t < s2) red[t] += red[t + s2]; __syncthreads(); }
  if (t == 0) {
    out[LOSS_OFF] = (float)(0.25 * ssq / 33554432.0);
    out[PERP_OFF] = (float)exp(-red[0]);
  }
}

extern "C" void kernel_launch(void* const* d_in, const int* in_sizes, int n_in,
                              void* d_out, int out_size, void* d_ws, size_t ws_size,
                              hipStream_t stream) {
  // Bind inputs by SIZE: z has 33,554,432 elems, codebook 262,144.
  const float* z;
  const float* cb;
  if (in_sizes[0] == NR * DD) { z = (const float*)d_in[0]; cb = (const float*)d_in[1]; }
  else                        { cb = (const float*)d_in[0]; z = (const float*)d_in[1]; }

  float* out = (float*)d_out;
  char* ws = (char*)d_ws;
  int*            counts = (int*)(ws + WS_CNT);
  float*          c2n    = (float*)(ws + WS_C2N);
  double*         bssp   = (double*)(ws + WS_BSS);
  unsigned short* cbs    = (unsigned short*)(ws + WS_CBS);

  hipMemsetAsync(counts, 0, 4096, stream);
  vqz_c2<<<4, 256, 0, stream>>>(cb, c2n);
  vqz_cbsplit<<<128, 256, 0, stream>>>(cb, cbs);
  vqz_main<<<NR / 128, 256, 0, stream>>>(z, cb, cbs, c2n, out, counts, bssp);
  vqz_final<<<1, 256, 0, stream>>>(counts, bssp, out);
}